// Round 1
// 200.839 us; speedup vs baseline: 1.0442x; 1.0442x over previous
//
#include <hip/hip_runtime.h>
#include <hip/hip_bf16.h>
#include <math.h>

constexpr int B_ = 8;
constexpr int C_ = 256;
constexpr int N_ = 2048;
constexpr int CN_ = C_ * N_;        // 524288
constexpr int TOT_ = B_ * C_ * N_;  // 4194304
constexpr int NTILES = 16;          // 128-wide strips
constexpr int NPAIRS = 136;         // triangular tiles per batch

typedef __attribute__((ext_vector_type(8))) short bf16x8;
typedef __attribute__((ext_vector_type(4))) float f32x4;

__device__ __forceinline__ void g2l16(const void* g, void* l) {
    __builtin_amdgcn_global_load_lds(
        (const __attribute__((address_space(1))) void*)g,
        (__attribute__((address_space(3))) void*)l, 16, 0, 0);
}

__device__ __forceinline__ unsigned short bits(__hip_bfloat16 h) {
    union { __hip_bfloat16 b; unsigned short u; } cv;
    cv.b = h;
    return cv.u;
}

__device__ __forceinline__ float b2f(short s) {
    union { float f; unsigned u; } cv;
    cv.u = ((unsigned)(unsigned short)s) << 16;
    return cv.f;
}

// ----------------------------------------- convert (+ partial norms) -------
// grid = 1024 blocks (batch = blk&7 -> XCD-local), 256 threads.
// 64c x 64n tile: transpose, bf16 hi/lo split, atomic norm partial.
__global__ __launch_bounds__(256) void convert_kernel(const float* __restrict__ x,
                                                      __hip_bfloat16* __restrict__ hiT,
                                                      __hip_bfloat16* __restrict__ loT,
                                                      float* __restrict__ normacc) {
    const int blk = blockIdx.x;
    const int batch = blk & 7;
    const int nt = (blk >> 3) & 31;
    const int ctile = blk >> 8;
    const int n0 = nt << 6, c0 = ctile << 6;
    const int t = threadIdx.x;
    const int i = t & 63, j = t >> 6;

    __shared__ float tb[64][65];
    __shared__ float red[4][64];

    float s = 0.f;
    const float* xp = x + (size_t)batch * CN_ + (size_t)c0 * N_ + n0 + i;
#pragma unroll 4
    for (int r = 0; r < 16; ++r) {
        const int cl = j + r * 4;
        const float v = xp[(size_t)cl * N_];
        tb[cl][i] = v;
        s += v * v;
    }
    red[j][i] = s;
    __syncthreads();

    const int cp = t & 31;  // c-pair
    const int c2 = cp << 1;
    const int nb = t >> 5;  // 8 n-groups
#pragma unroll 4
    for (int r = 0; r < 8; ++r) {
        const int n = nb + r * 8;
        const float v0 = tb[c2][n], v1 = tb[c2 + 1][n];
        const size_t o = ((size_t)batch * N_ + n0 + n) * C_ + c0 + c2;
        const __hip_bfloat16 h0 = __float2bfloat16(v0);
        const __hip_bfloat16 h1 = __float2bfloat16(v1);
        const __hip_bfloat16 g0 = __float2bfloat16(v0 - __bfloat162float(h0));
        const __hip_bfloat16 g1 = __float2bfloat16(v1 - __bfloat162float(h1));
        ((unsigned*)hiT)[o >> 1] = ((unsigned)bits(h1) << 16) | bits(h0);
        ((unsigned*)loT)[o >> 1] = ((unsigned)bits(g1) << 16) | bits(g0);
    }
    if (j == 0) {
        const float tt = red[0][i] + red[1][i] + red[2][i] + red[3][i];
        atomicAdd(normacc + batch * N_ + n0 + i, tt);
    }
}

__global__ void rnorm_fin_kernel(const float* __restrict__ normacc,
                                 float* __restrict__ rnorm) {
    const int t = blockIdx.x * 256 + threadIdx.x;  // 16384
    rnorm[t] = 1.0f / sqrtf(normacc[t] + 256.0f * 1e-6f);
}

// ------------------------------- gram (MFMA, triangular) + argmax ----------
// grid = B * 136 blocks of 256 (4 waves); batch = blk & 7 (XCD-local L2).
// 128x128 tile, BK=32, bn<=bm. sim = hi*hi + hi*lo + lo*hi FUSED in one
// K-pass: LDS rows pack [hi k0..31 | lo k0..31] (128B), so all three
// products are computed per staged tile. Double-buffered with prefetch:
// stage(t+1) issued BEFORE ds_read/MFMA of tile t; the single
// __syncthreads() per step (implicit vmcnt(0)) is the pipeline drain.
// Off-diag blocks emit row AND col argmax. Epilogue overlays As[0] (LDS=64KB).
__device__ __forceinline__ void stage_tile(const __hip_bfloat16* __restrict__ hiT,
                                           const __hip_bfloat16* __restrict__ loT,
                                           size_t base, int kb, short* dst, int tid) {
    // 16KB tile: 128 rows x 8 granules(16B). granule<4 -> hi, >=4 -> lo.
    // XOR swizzle applied on the GLOBAL source (LDS stays linear for g2l16).
#pragma unroll
    for (int pp = 0; pp < 4; ++pp) {
        const int slot = tid + pp * 256;
        const int r = slot >> 3, sidx = slot & 7;
        const int sw = sidx ^ (r & 7);  // logical granule (self-inverse swizzle)
        const size_t goff = base + (size_t)r * C_ + kb + (sw & 3) * 8;
        const __hip_bfloat16* src = (sw < 4) ? (hiT + goff) : (loT + goff);
        g2l16(src, dst + slot * 8);
    }
}

__global__ __launch_bounds__(256, 2) void gram_mfma_kernel(
        const __hip_bfloat16* __restrict__ hiT, const __hip_bfloat16* __restrict__ loT,
        const float* __restrict__ rnorm,
        float* __restrict__ pval, int* __restrict__ pidx, float* __restrict__ pval2) {
    const int blk = blockIdx.x;
    const int batch = blk & 7;
    int p = blk >> 3;  // 0..135
    int bn = 0;
    while (p >= NTILES - bn) { p -= NTILES - bn; ++bn; }
    const int bm = bn + p;
    const bool diag = (bn == bm);
    const int n0 = bn << 7, m0 = bm << 7;

    __shared__ short As[2][128 * 64];
    __shared__ short Bs[2][128 * 64];
    // epilogue arrays overlaid on As[0] (safe: only used after final barrier)
    short* ov = &As[0][0];
    float (*rv1)[2] = (float(*)[2])(ov + 0);
    int (*ri1)[2] = (int(*)[2])(ov + 512);
    float (*rv2)[2] = (float(*)[2])(ov + 1024);
    float (*cv1)[2] = (float(*)[2])(ov + 1536);
    int (*ci1)[2] = (int(*)[2])(ov + 2048);
    float (*cv2)[2] = (float(*)[2])(ov + 2560);
    float* rnA = (float*)(ov + 3072);

    const int tid = threadIdx.x;
    const int l = tid & 63, w = tid >> 6;
    const int lm = l & 15, q = l >> 4;
    const int wn = (w >> 1) << 6, wm = (w & 1) << 6;

    f32x4 acc[4][4];
#pragma unroll
    for (int rt = 0; rt < 4; ++rt)
#pragma unroll
        for (int ct = 0; ct < 4; ++ct) acc[rt][ct] = (f32x4){0.f, 0.f, 0.f, 0.f};

    const size_t bbase = (size_t)batch * CN_;
    const size_t abase = bbase + (size_t)n0 * C_;
    const size_t bbase2 = bbase + (size_t)m0 * C_;

    // prologue: stage K-tile 0 into buffer 0
    stage_tile(hiT, loT, abase, 0, &As[0][0], tid);
    stage_tile(hiT, loT, bbase2, 0, &Bs[0][0], tid);
    __syncthreads();

    for (int kt = 0; kt < 8; ++kt) {
        const int cur = kt & 1;
        if (kt < 7) {  // prefetch next K-tile into the other buffer
            const int kb = (kt + 1) << 5;
            stage_tile(hiT, loT, abase, kb, &As[cur ^ 1][0], tid);
            stage_tile(hiT, loT, bbase2, kb, &Bs[cur ^ 1][0], tid);
        }
        short* Ac = &As[cur][0];
        short* Bc = &Bs[cur][0];
        bf16x8 ah[4], al[4], bh[4], bl[4];
        const int x7 = lm & 7;
#pragma unroll
        for (int rt = 0; rt < 4; ++rt) {
            const int row = wn + rt * 16 + lm;
            ah[rt] = *(const bf16x8*)(Ac + row * 64 + ((q ^ x7) * 8));
            al[rt] = *(const bf16x8*)(Ac + row * 64 + (((4 | q) ^ x7) * 8));
        }
#pragma unroll
        for (int ct = 0; ct < 4; ++ct) {
            const int row = wm + ct * 16 + lm;
            bh[ct] = *(const bf16x8*)(Bc + row * 64 + ((q ^ x7) * 8));
            bl[ct] = *(const bf16x8*)(Bc + row * 64 + (((4 | q) ^ x7) * 8));
        }
#pragma unroll
        for (int rt = 0; rt < 4; ++rt)
#pragma unroll
            for (int ct = 0; ct < 4; ++ct) {
                acc[rt][ct] = __builtin_amdgcn_mfma_f32_16x16x32_bf16(
                    ah[rt], bh[ct], acc[rt][ct], 0, 0, 0);
                acc[rt][ct] = __builtin_amdgcn_mfma_f32_16x16x32_bf16(
                    ah[rt], bl[ct], acc[rt][ct], 0, 0, 0);
                acc[rt][ct] = __builtin_amdgcn_mfma_f32_16x16x32_bf16(
                    al[rt], bh[ct], acc[rt][ct], 0, 0, 0);
            }
        __syncthreads();  // drains vmcnt (next tile staged) + all LDS reads of cur
    }

    // all LDS reads drained by final loop barrier; safe to overlay As[0]
    if (tid < 128) rnA[tid] = rnorm[batch * N_ + n0 + tid];

    // ---- row path: rows n (n-strip), candidates m (m-strip), scale rnorm[m]
    float rnm[4];
#pragma unroll
    for (int ct = 0; ct < 4; ++ct) rnm[ct] = rnorm[batch * N_ + m0 + wm + ct * 16 + lm];

#pragma unroll
    for (int rt = 0; rt < 4; ++rt) {
#pragma unroll
        for (int r = 0; r < 4; ++r) {
            const int nrow = n0 + wn + rt * 16 + q * 4 + r;
            float v1 = -3.4e38f, v2 = -3.4e38f;
            int i1 = 0x7fffffff;
#pragma unroll
            for (int ct = 0; ct < 4; ++ct) {
                const int m = m0 + wm + ct * 16 + lm;
                const float v = acc[rt][ct][r] * rnm[ct];
                if (m == nrow) continue;
                if (v > v1) { v2 = v1; v1 = v; i1 = m; }
                else if (v > v2) v2 = v;
            }
#pragma unroll
            for (int d = 1; d < 16; d <<= 1) {
                const float ov1 = __shfl_xor(v1, d, 64);
                const int oi1 = __shfl_xor(i1, d, 64);
                const float ov2 = __shfl_xor(v2, d, 64);
                if (ov1 > v1 || (ov1 == v1 && oi1 < i1)) {
                    v2 = fmaxf(v1, ov2); v1 = ov1; i1 = oi1;
                } else {
                    v2 = fmaxf(v2, ov1);
                }
            }
            if (lm == 0) {
                const int rloc = wn + rt * 16 + q * 4 + r;
                rv1[rloc][w & 1] = v1;
                ri1[rloc][w & 1] = i1;
                rv2[rloc][w & 1] = v2;
            }
        }
    }
    __syncthreads();  // rnA + rv* visible

    // ---- col path: rows m (m-strip), candidates n (n-strip), scale rnorm[n]
    if (!diag) {
        float rnn[4][4];
#pragma unroll
        for (int rt = 0; rt < 4; ++rt)
#pragma unroll
            for (int r = 0; r < 4; ++r) rnn[rt][r] = rnA[wn + rt * 16 + q * 4 + r];
#pragma unroll
        for (int ct = 0; ct < 4; ++ct) {
            float v1 = -3.4e38f, v2 = -3.4e38f;
            int i1 = 0x7fffffff;
#pragma unroll
            for (int rt = 0; rt < 4; ++rt) {
#pragma unroll
                for (int r = 0; r < 4; ++r) {
                    const float v = acc[rt][ct][r] * rnn[rt][r];
                    const int nn = n0 + wn + rt * 16 + q * 4 + r;
                    if (v > v1) { v2 = v1; v1 = v; i1 = nn; }
                    else if (v > v2) v2 = v;
                }
            }
#pragma unroll
            for (int d = 16; d < 64; d <<= 1) {
                const float ov1 = __shfl_xor(v1, d, 64);
                const int oi1 = __shfl_xor(i1, d, 64);
                const float ov2 = __shfl_xor(v2, d, 64);
                if (ov1 > v1 || (ov1 == v1 && oi1 < i1)) {
                    v2 = fmaxf(v1, ov2); v1 = ov1; i1 = oi1;
                } else {
                    v2 = fmaxf(v2, ov1);
                }
            }
            if (q == 0) {
                const int mloc = wm + ct * 16 + lm;
                cv1[mloc][w >> 1] = v1;
                ci1[mloc][w >> 1] = i1;
                cv2[mloc][w >> 1] = v2;
            }
        }
    }
    __syncthreads();

    if (tid < 128) {
        // row result -> slot bm, rows n-strip
        {
            float v1 = rv1[tid][0]; int i1 = ri1[tid][0]; float v2 = rv2[tid][0];
            const float ov1 = rv1[tid][1]; const int oi1 = ri1[tid][1]; const float ov2 = rv2[tid][1];
            if (ov1 > v1 || (ov1 == v1 && oi1 < i1)) { v2 = fmaxf(v1, ov2); v1 = ov1; i1 = oi1; }
            else v2 = fmaxf(v2, ov1);
            const size_t gi = (size_t)(batch * NTILES + bm) * N_ + n0 + tid;
            pval[gi] = v1; pidx[gi] = i1; pval2[gi] = v2;
        }
        // col result -> slot bn, rows m-strip
        if (!diag) {
            float v1 = cv1[tid][0]; int i1 = ci1[tid][0]; float v2 = cv2[tid][0];
            const float ov1 = cv1[tid][1]; const int oi1 = ci1[tid][1]; const float ov2 = cv2[tid][1];
            if (ov1 > v1 || (ov1 == v1 && oi1 < i1)) { v2 = fmaxf(v1, ov2); v1 = ov1; i1 = oi1; }
            else v2 = fmaxf(v2, ov1);
            const size_t gi = (size_t)(batch * NTILES + bn) * N_ + m0 + tid;
            pval[gi] = v1; pidx[gi] = i1; pval2[gi] = v2;
        }
    }
}

// -------------------------------------------------------------- combine ----
__global__ void combine_kernel(const float* __restrict__ pval, const int* __restrict__ pidx,
                               const float* __restrict__ pval2, int* __restrict__ fidx,
                               int* __restrict__ rcnt, int* __restrict__ ridx) {
    const int t = blockIdx.x * 256 + threadIdx.x;  // 16384
    const int batch = t >> 11, n = t & 2047;
    float v1 = -3.4e38f, v2 = -3.4e38f;
    int i1 = 0x7fffffff;
    for (int s = 0; s < NTILES; ++s) {
        const size_t gi = (size_t)(batch * NTILES + s) * N_ + n;
        const float ov1 = pval[gi]; const int oi1 = pidx[gi]; const float ov2 = pval2[gi];
        if (ov1 > v1 || (ov1 == v1 && oi1 < i1)) { v2 = fmaxf(v1, ov2); v1 = ov1; i1 = oi1; }
        else v2 = fmaxf(v2, ov1);
    }
    fidx[t] = i1;
    if (v1 - v2 < 1e-4f) {
        const int slot = atomicAdd(rcnt, 1);
        ridx[slot] = t;
    }
}

// --------------------------------------------------------------- rescue ----
// Exact fp32 re-argmax for near-tie rows, reading original x (coalesced over m).
__global__ __launch_bounds__(256) void rescue_kernel(const float* __restrict__ x,
                                                     const float* __restrict__ rnorm,
                                                     const int* __restrict__ rcnt,
                                                     const int* __restrict__ ridx,
                                                     int* __restrict__ fidx) {
    const int cnt = *rcnt;
    const int tid = threadIdx.x;
    __shared__ float bv[256];
    __shared__ int bi[256];
    for (int rr = blockIdx.x; rr < cnt; rr += gridDim.x) {
        const int t = ridx[rr];
        const int batch = t >> 11, n = t & 2047;
        const float* xb = x + (size_t)batch * CN_;
        float s[8];
#pragma unroll
        for (int k = 0; k < 8; ++k) s[k] = 0.f;
        for (int c = 0; c < C_; ++c) {
            const float xc = xb[(size_t)c * N_ + n];
            const float* xr = xb + (size_t)c * N_;
#pragma unroll
            for (int k = 0; k < 8; ++k) s[k] += xc * xr[tid + (k << 8)];
        }
        float best = -3.4e38f;
        int besti = 0x7fffffff;
#pragma unroll
        for (int k = 0; k < 8; ++k) {
            const int m = tid + (k << 8);
            const float v = s[k] * rnorm[batch * N_ + m];
            if (m != n && v > best) { best = v; besti = m; }
        }
        bv[tid] = best; bi[tid] = besti;
        __syncthreads();
        for (int sft = 128; sft > 0; sft >>= 1) {
            if (tid < sft) {
                const float ov = bv[tid + sft]; const int oi = bi[tid + sft];
                if (ov > bv[tid] || (ov == bv[tid] && oi < bi[tid])) { bv[tid] = ov; bi[tid] = oi; }
            }
            __syncthreads();
        }
        if (tid == 0) fidx[t] = bi[0];
        __syncthreads();
    }
}

// ------------------------------- finish: gate softmax + gather + outputs ---
// grid = 1024 blocks (batch = blk&7, 128 ntiles of 16 n), 256 threads.
__global__ __launch_bounds__(256) void finish_kernel(const float* __restrict__ x,
                                                     const __hip_bfloat16* __restrict__ hiT,
                                                     const __hip_bfloat16* __restrict__ loT,
                                                     const float* __restrict__ W,
                                                     const int* __restrict__ fidx,
                                                     float* __restrict__ out) {
    const int batch = blockIdx.x & 7;
    const int nt = blockIdx.x >> 3;  // 0..127
    const int n0 = nt << 4;
    const int t = threadIdx.x;
    const int i = t & 15, cg = t >> 4;  // cg 0..15, 16 c each

    __shared__ float Wl[1024];
    __shared__ int il[16];
    __shared__ float l0r[16][17], l1r[16][17];
    __shared__ float w0s[16], w1s[16];

    for (int u = t; u < 1024; u += 256) Wl[u] = W[u];
    if (t < 16) il[t] = fidx[batch * N_ + n0 + t];
    __syncthreads();

    const float* xb = x + (size_t)batch * CN_ + n0 + i;
    const int myidx = il[i];
    const size_t row = ((size_t)batch * N_ + myidx) * C_ + cg * 16;

    float fvv[16];
    {
        const bf16x8* hp = (const bf16x8*)(hiT + row);
        const bf16x8* lp = (const bf16x8*)(loT + row);
#pragma unroll
        for (int v8 = 0; v8 < 2; ++v8) {
            const bf16x8 h = hp[v8];
            const bf16x8 g = lp[v8];
#pragma unroll
            for (int e = 0; e < 8; ++e) fvv[v8 * 8 + e] = b2f(h[e]) + b2f(g[e]);
        }
    }

    float l0 = 0.f, l1 = 0.f;
#pragma unroll
    for (int cc = 0; cc < 16; ++cc) {
        const int c = cg * 16 + cc;
        const float xv = xb[(size_t)c * N_];
        l0 += xv * Wl[c] + fvv[cc] * Wl[256 + c];
        l1 += xv * Wl[512 + c] + fvv[cc] * Wl[768 + c];
    }
    l0r[cg][i] = l0;
    l1r[cg][i] = l1;
    __syncthreads();
    if (t < 16) {
        float L0 = 0.f, L1 = 0.f;
#pragma unroll
        for (int g = 0; g < 16; ++g) { L0 += l0r[g][t]; L1 += l1r[g][t]; }
        const float mx = fmaxf(L0, L1);
        const float e0 = expf(L0 - mx);
        const float e1 = expf(L1 - mx);
        const float inv = 1.0f / (e0 + e1);
        w0s[t] = e0 * inv;
        w1s[t] = e1 * inv;
    }
    __syncthreads();
    const float w0 = w0s[i], w1 = w1s[i];

#pragma unroll
    for (int cc = 0; cc < 16; ++cc) {
        const int c = cg * 16 + cc;
        const size_t off = (size_t)batch * CN_ + (size_t)c * N_ + n0 + i;
        const float xv = xb[(size_t)c * N_];  // L1-hot re-read
        out[off] = xv * w0 + fvv[cc] * w1;
        out[TOT_ + off] = fvv[cc];
    }
}

// ---------------------------------------------------------------------------
extern "C" void kernel_launch(void* const* d_in, const int* in_sizes, int n_in,
                              void* d_out, int out_size, void* d_ws, size_t ws_size,
                              hipStream_t stream) {
    const float* x = (const float*)d_in[0];
    const float* W = (const float*)d_in[1];
    float* out = (float*)d_out;

    const size_t BF_BYTES = (size_t)TOT_ * 2;             // 8.39 MB each
    const size_t NORM_BYTES = (size_t)B_ * N_ * 4;        // 64 KB
    const size_t P_BYTES = (size_t)B_ * NTILES * N_ * 4;  // 1 MB each

    uint8_t* p = (uint8_t*)d_ws;
    __hip_bfloat16* hiT = (__hip_bfloat16*)p; p += BF_BYTES;
    __hip_bfloat16* loT = (__hip_bfloat16*)p; p += BF_BYTES;
    float* rnorm = (float*)p; p += NORM_BYTES;
    float* normacc = (float*)p; p += NORM_BYTES;
    float* pval = (float*)p; p += P_BYTES;
    int* pidx = (int*)p; p += P_BYTES;
    float* pval2 = (float*)p; p += P_BYTES;
    int* fidx = (int*)p; p += NORM_BYTES;
    int* rcnt = (int*)p; p += 256;
    int* ridx = (int*)p; p += NORM_BYTES;

    hipMemsetAsync(rcnt, 0, 4, stream);
    hipMemsetAsync(normacc, 0, NORM_BYTES, stream);
    convert_kernel<<<1024, 256, 0, stream>>>(x, hiT, loT, normacc);
    rnorm_fin_kernel<<<64, 256, 0, stream>>>(normacc, rnorm);
    gram_mfma_kernel<<<B_ * NPAIRS, 256, 0, stream>>>(hiT, loT, rnorm, pval, pidx, pval2);
    combine_kernel<<<64, 256, 0, stream>>>(pval, pidx, pval2, fidx, rcnt, ridx);
    rescue_kernel<<<64, 256, 0, stream>>>(x, rnorm, rcnt, ridx, fidx);
    finish_kernel<<<1024, 256, 0, stream>>>(x, hiT, loT, W, fidx, out);
}

// Round 2
// 180.349 us; speedup vs baseline: 1.1628x; 1.1136x over previous
//
#include <hip/hip_runtime.h>
#include <hip/hip_bf16.h>
#include <math.h>

constexpr int B_ = 8;
constexpr int C_ = 256;
constexpr int N_ = 2048;
constexpr int CN_ = C_ * N_;        // 524288
constexpr int TOT_ = B_ * C_ * N_;  // 4194304
constexpr int NTILES = 16;          // 128-wide strips
constexpr int NPAIRS = 136;         // triangular tiles per batch

typedef __attribute__((ext_vector_type(8))) short bf16x8;
typedef __attribute__((ext_vector_type(4))) float f32x4;

__device__ __forceinline__ void g2l16(const void* g, void* l) {
    __builtin_amdgcn_global_load_lds(
        (const __attribute__((address_space(1))) void*)g,
        (__attribute__((address_space(3))) void*)l, 16, 0, 0);
}

__device__ __forceinline__ unsigned short bits(__hip_bfloat16 h) {
    union { __hip_bfloat16 b; unsigned short u; } cv;
    cv.b = h;
    return cv.u;
}

__device__ __forceinline__ float b2f(short s) {
    union { float f; unsigned u; } cv;
    cv.u = ((unsigned)(unsigned short)s) << 16;
    return cv.f;
}

// sortable packed key: (monotone float bits << 32) | (2047 - m)  [lower m wins ties]
__device__ __forceinline__ unsigned long long packkey(float v, int m) {
    const unsigned b = __float_as_uint(v);
    const unsigned u = (b & 0x80000000u) ? ~b : (b | 0x80000000u);
    return ((unsigned long long)u << 32) | (unsigned)(2047 - m);
}

// ----------------------------------------- convert (+ partial norms) -------
// grid = 1024 blocks (batch = blk&7 -> XCD-local), 256 threads.
// 64c x 64n tile: transpose, bf16 hi/lo split, atomic norm partial.
__global__ __launch_bounds__(256) void convert_kernel(const float* __restrict__ x,
                                                      __hip_bfloat16* __restrict__ hiT,
                                                      __hip_bfloat16* __restrict__ loT,
                                                      float* __restrict__ normacc) {
    const int blk = blockIdx.x;
    const int batch = blk & 7;
    const int nt = (blk >> 3) & 31;
    const int ctile = blk >> 8;
    const int n0 = nt << 6, c0 = ctile << 6;
    const int t = threadIdx.x;
    const int i = t & 63, j = t >> 6;

    __shared__ float tb[64][65];
    __shared__ float red[4][64];

    float s = 0.f;
    const float* xp = x + (size_t)batch * CN_ + (size_t)c0 * N_ + n0 + i;
#pragma unroll 4
    for (int r = 0; r < 16; ++r) {
        const int cl = j + r * 4;
        const float v = xp[(size_t)cl * N_];
        tb[cl][i] = v;
        s += v * v;
    }
    red[j][i] = s;
    __syncthreads();

    const int cp = t & 31;  // c-pair
    const int c2 = cp << 1;
    const int nb = t >> 5;  // 8 n-groups
#pragma unroll 4
    for (int r = 0; r < 8; ++r) {
        const int n = nb + r * 8;
        const float v0 = tb[c2][n], v1 = tb[c2 + 1][n];
        const size_t o = ((size_t)batch * N_ + n0 + n) * C_ + c0 + c2;
        const __hip_bfloat16 h0 = __float2bfloat16(v0);
        const __hip_bfloat16 h1 = __float2bfloat16(v1);
        const __hip_bfloat16 g0 = __float2bfloat16(v0 - __bfloat162float(h0));
        const __hip_bfloat16 g1 = __float2bfloat16(v1 - __bfloat162float(h1));
        ((unsigned*)hiT)[o >> 1] = ((unsigned)bits(h1) << 16) | bits(h0);
        ((unsigned*)loT)[o >> 1] = ((unsigned)bits(g1) << 16) | bits(g0);
    }
    if (j == 0) {
        const float tt = red[0][i] + red[1][i] + red[2][i] + red[3][i];
        atomicAdd(normacc + batch * N_ + n0 + i, tt);
    }
}

__global__ void rnorm_fin_kernel(const float* __restrict__ normacc,
                                 float* __restrict__ rnorm) {
    const int t = blockIdx.x * 256 + threadIdx.x;  // 16384
    rnorm[t] = 1.0f / sqrtf(normacc[t] + 256.0f * 1e-6f);
}

// ------------------------------- gram (MFMA, triangular) + argmax ----------
// grid = B * 136 blocks of 256 (4 waves); batch = blk & 7 (XCD-local L2).
// 128x128 tile, BK=32, bn<=bm. sim = hi*hi + hi*lo + lo*hi fused per K-pass:
// LDS rows pack [hi k0..31 | lo k0..31] (128B). TRUE double-buffer: 4 separate
// __shared__ objects + fully-unrolled kt loop (static buffer refs) so alias
// analysis proves stage(next) and ds_read(cur) independent -> no vmcnt(0)
// before the ds_reads; the only drain is at the end-of-iteration barrier,
// hidden under 48 MFMA + 16 ds_read. All per-lane addresses hoisted.
__global__ __launch_bounds__(256, 2) void gram_mfma_kernel(
        const __hip_bfloat16* __restrict__ hiT, const __hip_bfloat16* __restrict__ loT,
        const float* __restrict__ rnorm,
        float* __restrict__ pval, int* __restrict__ pidx, float* __restrict__ pval2) {
    const int blk = blockIdx.x;
    const int batch = blk & 7;
    int p = blk >> 3;  // 0..135
    int bn = 0;
    while (p >= NTILES - bn) { p -= NTILES - bn; ++bn; }
    const int bm = bn + p;
    const bool diag = (bn == bm);
    const int n0 = bn << 7, m0 = bm << 7;

    __shared__ short As0[128 * 64];
    __shared__ short As1[128 * 64];
    __shared__ short Bs0[128 * 64];
    __shared__ short Bs1[128 * 64];
    // epilogue arrays overlaid on As0 (safe: only used after final barrier)
    short* ov = &As0[0];
    float (*rv1)[2] = (float(*)[2])(ov + 0);
    int (*ri1)[2] = (int(*)[2])(ov + 512);
    float (*rv2)[2] = (float(*)[2])(ov + 1024);
    float (*cv1)[2] = (float(*)[2])(ov + 1536);
    int (*ci1)[2] = (int(*)[2])(ov + 2048);
    float (*cv2)[2] = (float(*)[2])(ov + 2560);
    float* rnA = (float*)(ov + 3072);

    const int tid = threadIdx.x;
    const int l = tid & 63, w = tid >> 6;
    const int lm = l & 15, q = l >> 4;
    const int x7 = lm & 7;
    const int wn = (w >> 1) << 6, wm = (w & 1) << 6;

    // ---- hoisted per-lane stage addresses (loop-invariant) ----
    const size_t bbase = (size_t)batch * CN_;
    const short* gA[4];
    const short* gB[4];
    int ldsoff[4];
#pragma unroll
    for (int pp = 0; pp < 4; ++pp) {
        const int slot = tid + pp * 256;
        const int r = slot >> 3, sidx = slot & 7;
        const int sw = sidx ^ (r & 7);  // XOR swizzle (self-inverse)
        const short* base = (const short*)((sw < 4) ? hiT : loT);
        gA[pp] = base + bbase + (size_t)(n0 + r) * C_ + (sw & 3) * 8;
        gB[pp] = base + bbase + (size_t)(m0 + r) * C_ + (sw & 3) * 8;
        ldsoff[pp] = slot * 8;
    }
    // ---- hoisted per-lane ds_read offsets (shorts) ----
    int aoff[8], boff[8];  // [rt*2 + {hi,lo}]
#pragma unroll
    for (int rt = 0; rt < 4; ++rt) {
        const int ra = wn + rt * 16 + lm;
        const int rb = wm + rt * 16 + lm;
        aoff[rt * 2] = ra * 64 + ((q ^ x7) * 8);
        aoff[rt * 2 + 1] = ra * 64 + (((4 | q) ^ x7) * 8);
        boff[rt * 2] = rb * 64 + ((q ^ x7) * 8);
        boff[rt * 2 + 1] = rb * 64 + (((4 | q) ^ x7) * 8);
    }

    f32x4 acc[4][4];
#pragma unroll
    for (int rt = 0; rt < 4; ++rt)
#pragma unroll
        for (int ct = 0; ct < 4; ++ct) acc[rt][ct] = (f32x4){0.f, 0.f, 0.f, 0.f};

    // prologue: stage K-tile 0 into buffer 0
#pragma unroll
    for (int pp = 0; pp < 4; ++pp) {
        g2l16(gA[pp], As0 + ldsoff[pp]);
        g2l16(gB[pp], Bs0 + ldsoff[pp]);
    }
    __syncthreads();

#pragma unroll
    for (int kt = 0; kt < 8; ++kt) {
        short* Ac = (kt & 1) ? As1 : As0;
        short* Bc = (kt & 1) ? Bs1 : Bs0;
        if (kt < 7) {  // prefetch next K-tile into the other (distinct) buffer
            short* An = (kt & 1) ? As0 : As1;
            short* Bn = (kt & 1) ? Bs0 : Bs1;
#pragma unroll
            for (int pp = 0; pp < 4; ++pp) {
                g2l16(gA[pp] + (kt + 1) * 32, An + ldsoff[pp]);
                g2l16(gB[pp] + (kt + 1) * 32, Bn + ldsoff[pp]);
            }
        }
        bf16x8 ah[4], al[4], bh[4], bl[4];
#pragma unroll
        for (int rt = 0; rt < 4; ++rt) {
            ah[rt] = *(const bf16x8*)(Ac + aoff[rt * 2]);
            al[rt] = *(const bf16x8*)(Ac + aoff[rt * 2 + 1]);
        }
#pragma unroll
        for (int ct = 0; ct < 4; ++ct) {
            bh[ct] = *(const bf16x8*)(Bc + boff[ct * 2]);
            bl[ct] = *(const bf16x8*)(Bc + boff[ct * 2 + 1]);
        }
#pragma unroll
        for (int rt = 0; rt < 4; ++rt)
#pragma unroll
            for (int ct = 0; ct < 4; ++ct) {
                acc[rt][ct] = __builtin_amdgcn_mfma_f32_16x16x32_bf16(
                    ah[rt], bh[ct], acc[rt][ct], 0, 0, 0);
                acc[rt][ct] = __builtin_amdgcn_mfma_f32_16x16x32_bf16(
                    ah[rt], bl[ct], acc[rt][ct], 0, 0, 0);
                acc[rt][ct] = __builtin_amdgcn_mfma_f32_16x16x32_bf16(
                    al[rt], bh[ct], acc[rt][ct], 0, 0, 0);
            }
        __syncthreads();  // drains vmcnt (next tile staged) + all LDS reads of cur
    }

    // all LDS reads drained by final loop barrier; safe to overlay As0
    if (tid < 128) rnA[tid] = rnorm[batch * N_ + n0 + tid];

    // ---- row path: rows n (n-strip), candidates m (m-strip), scale rnorm[m]
    float rnm[4];
#pragma unroll
    for (int ct = 0; ct < 4; ++ct) rnm[ct] = rnorm[batch * N_ + m0 + wm + ct * 16 + lm];

#pragma unroll
    for (int rt = 0; rt < 4; ++rt) {
#pragma unroll
        for (int r = 0; r < 4; ++r) {
            const int nrow = n0 + wn + rt * 16 + q * 4 + r;
            float v1 = -3.4e38f, v2 = -3.4e38f;
            int i1 = 0x7fffffff;
#pragma unroll
            for (int ct = 0; ct < 4; ++ct) {
                const int m = m0 + wm + ct * 16 + lm;
                const float v = acc[rt][ct][r] * rnm[ct];
                if (m == nrow) continue;
                if (v > v1) { v2 = v1; v1 = v; i1 = m; }
                else if (v > v2) v2 = v;
            }
#pragma unroll
            for (int d = 1; d < 16; d <<= 1) {
                const float ov1 = __shfl_xor(v1, d, 64);
                const int oi1 = __shfl_xor(i1, d, 64);
                const float ov2 = __shfl_xor(v2, d, 64);
                if (ov1 > v1 || (ov1 == v1 && oi1 < i1)) {
                    v2 = fmaxf(v1, ov2); v1 = ov1; i1 = oi1;
                } else {
                    v2 = fmaxf(v2, ov1);
                }
            }
            if (lm == 0) {
                const int rloc = wn + rt * 16 + q * 4 + r;
                rv1[rloc][w & 1] = v1;
                ri1[rloc][w & 1] = i1;
                rv2[rloc][w & 1] = v2;
            }
        }
    }
    __syncthreads();  // rnA + rv* visible

    // ---- col path: rows m (m-strip), candidates n (n-strip), scale rnorm[n]
    if (!diag) {
        float rnn[4][4];
#pragma unroll
        for (int rt = 0; rt < 4; ++rt)
#pragma unroll
            for (int r = 0; r < 4; ++r) rnn[rt][r] = rnA[wn + rt * 16 + q * 4 + r];
#pragma unroll
        for (int ct = 0; ct < 4; ++ct) {
            float v1 = -3.4e38f, v2 = -3.4e38f;
            int i1 = 0x7fffffff;
#pragma unroll
            for (int rt = 0; rt < 4; ++rt) {
#pragma unroll
                for (int r = 0; r < 4; ++r) {
                    const float v = acc[rt][ct][r] * rnn[rt][r];
                    const int nn = n0 + wn + rt * 16 + q * 4 + r;
                    if (v > v1) { v2 = v1; v1 = v; i1 = nn; }
                    else if (v > v2) v2 = v;
                }
            }
#pragma unroll
            for (int d = 16; d < 64; d <<= 1) {
                const float ov1 = __shfl_xor(v1, d, 64);
                const int oi1 = __shfl_xor(i1, d, 64);
                const float ov2 = __shfl_xor(v2, d, 64);
                if (ov1 > v1 || (ov1 == v1 && oi1 < i1)) {
                    v2 = fmaxf(v1, ov2); v1 = ov1; i1 = oi1;
                } else {
                    v2 = fmaxf(v2, ov1);
                }
            }
            if (q == 0) {
                const int mloc = wm + ct * 16 + lm;
                cv1[mloc][w >> 1] = v1;
                ci1[mloc][w >> 1] = i1;
                cv2[mloc][w >> 1] = v2;
            }
        }
    }
    __syncthreads();

    if (tid < 128) {
        // row result -> slot bm, rows n-strip
        {
            float v1 = rv1[tid][0]; int i1 = ri1[tid][0]; float v2 = rv2[tid][0];
            const float ov1 = rv1[tid][1]; const int oi1 = ri1[tid][1]; const float ov2 = rv2[tid][1];
            if (ov1 > v1 || (ov1 == v1 && oi1 < i1)) { v2 = fmaxf(v1, ov2); v1 = ov1; i1 = oi1; }
            else v2 = fmaxf(v2, ov1);
            const size_t gi = (size_t)(batch * NTILES + bm) * N_ + n0 + tid;
            pval[gi] = v1; pidx[gi] = i1; pval2[gi] = v2;
        }
        // col result -> slot bn, rows m-strip
        if (!diag) {
            float v1 = cv1[tid][0]; int i1 = ci1[tid][0]; float v2 = cv2[tid][0];
            const float ov1 = cv1[tid][1]; const int oi1 = ci1[tid][1]; const float ov2 = cv2[tid][1];
            if (ov1 > v1 || (ov1 == v1 && oi1 < i1)) { v2 = fmaxf(v1, ov2); v1 = ov1; i1 = oi1; }
            else v2 = fmaxf(v2, ov1);
            const size_t gi = (size_t)(batch * NTILES + bn) * N_ + m0 + tid;
            pval[gi] = v1; pidx[gi] = i1; pval2[gi] = v2;
        }
    }
}

// -------------------------------------------------------------- combine ----
__global__ void combine_kernel(const float* __restrict__ pval, const int* __restrict__ pidx,
                               const float* __restrict__ pval2, int* __restrict__ fidx,
                               int* __restrict__ rcnt, int* __restrict__ ridx,
                               unsigned long long* __restrict__ pbest) {
    const int t = blockIdx.x * 256 + threadIdx.x;  // 16384
    const int batch = t >> 11, n = t & 2047;
    float v1 = -3.4e38f, v2 = -3.4e38f;
    int i1 = 0x7fffffff;
    for (int s = 0; s < NTILES; ++s) {
        const size_t gi = (size_t)(batch * NTILES + s) * N_ + n;
        const float ov1 = pval[gi]; const int oi1 = pidx[gi]; const float ov2 = pval2[gi];
        if (ov1 > v1 || (ov1 == v1 && oi1 < i1)) { v2 = fmaxf(v1, ov2); v1 = ov1; i1 = oi1; }
        else v2 = fmaxf(v2, ov1);
    }
    fidx[t] = i1;
    if (v1 - v2 < 1e-4f) {
        const int slot = atomicAdd(rcnt, 1);
        ridx[slot] = t;
        pbest[slot] = 0ull;
    }
}

// --------------------------------------------------------------- rescue ----
// Exact fp32 re-argmax for near-tie rows. Each work item = (row, 256-m chunk)
// so one row's 2MB L2 stream is split across 8 blocks; block-reduce then one
// packed-u64 atomicMax per (row, chunk-block).
__global__ __launch_bounds__(256) void rescue_kernel(const float* __restrict__ x,
                                                     const float* __restrict__ rnorm,
                                                     const int* __restrict__ rcnt,
                                                     const int* __restrict__ ridx,
                                                     unsigned long long* __restrict__ pbest) {
    const int cnt = *rcnt;
    const int nwork = cnt << 3;
    const int tid = threadIdx.x;
    __shared__ unsigned long long bk[256];
    for (int wi = blockIdx.x; wi < nwork; wi += gridDim.x) {
        const int rr = wi >> 3, ch = wi & 7;
        const int t = ridx[rr];
        const int batch = t >> 11, n = t & 2047;
        const int m = (ch << 8) + tid;
        const float* xb = x + (size_t)batch * CN_;
        float s0 = 0.f, s1 = 0.f, s2 = 0.f, s3 = 0.f;
        const float* xn = xb + n;
        const float* xm = xb + m;
#pragma unroll 4
        for (int c = 0; c < C_; c += 4) {
            s0 += xn[(size_t)(c + 0) * N_] * xm[(size_t)(c + 0) * N_];
            s1 += xn[(size_t)(c + 1) * N_] * xm[(size_t)(c + 1) * N_];
            s2 += xn[(size_t)(c + 2) * N_] * xm[(size_t)(c + 2) * N_];
            s3 += xn[(size_t)(c + 3) * N_] * xm[(size_t)(c + 3) * N_];
        }
        const float v = ((s0 + s1) + (s2 + s3)) * rnorm[batch * N_ + m];
        bk[tid] = (m == n) ? 0ull : packkey(v, m);
        __syncthreads();
        for (int sft = 128; sft > 0; sft >>= 1) {
            if (tid < sft) {
                const unsigned long long o = bk[tid + sft];
                if (o > bk[tid]) bk[tid] = o;
            }
            __syncthreads();
        }
        if (tid == 0) atomicMax(&pbest[rr], bk[0]);
        __syncthreads();
    }
}

__global__ void rescue_fin_kernel(const unsigned long long* __restrict__ pbest,
                                  const int* __restrict__ rcnt,
                                  const int* __restrict__ ridx,
                                  int* __restrict__ fidx) {
    const int rr = blockIdx.x * 256 + threadIdx.x;
    if (rr < *rcnt) {
        const unsigned long long k = pbest[rr];
        const int m = 2047 - (int)(unsigned)(k & 0xffffffffull);
        fidx[ridx[rr]] = m;
    }
}

// ------------------------------- finish: gate softmax + gather + outputs ---
// grid = 1024 blocks (batch = blk&7, 128 ntiles of 16 n), 256 threads.
__global__ __launch_bounds__(256) void finish_kernel(const float* __restrict__ x,
                                                     const __hip_bfloat16* __restrict__ hiT,
                                                     const __hip_bfloat16* __restrict__ loT,
                                                     const float* __restrict__ W,
                                                     const int* __restrict__ fidx,
                                                     float* __restrict__ out) {
    const int batch = blockIdx.x & 7;
    const int nt = blockIdx.x >> 3;  // 0..127
    const int n0 = nt << 4;
    const int t = threadIdx.x;
    const int i = t & 15, cg = t >> 4;  // cg 0..15, 16 c each

    __shared__ float Wl[1024];
    __shared__ int il[16];
    __shared__ float l0r[16][17], l1r[16][17];
    __shared__ float w0s[16], w1s[16];

    for (int u = t; u < 1024; u += 256) Wl[u] = W[u];
    if (t < 16) il[t] = fidx[batch * N_ + n0 + t];
    __syncthreads();

    const float* xb = x + (size_t)batch * CN_ + n0 + i;
    const int myidx = il[i];
    const size_t row = ((size_t)batch * N_ + myidx) * C_ + cg * 16;

    float fvv[16];
    {
        const bf16x8* hp = (const bf16x8*)(hiT + row);
        const bf16x8* lp = (const bf16x8*)(loT + row);
#pragma unroll
        for (int v8 = 0; v8 < 2; ++v8) {
            const bf16x8 h = hp[v8];
            const bf16x8 g = lp[v8];
#pragma unroll
            for (int e = 0; e < 8; ++e) fvv[v8 * 8 + e] = b2f(h[e]) + b2f(g[e]);
        }
    }

    float l0 = 0.f, l1 = 0.f;
#pragma unroll
    for (int cc = 0; cc < 16; ++cc) {
        const int c = cg * 16 + cc;
        const float xv = xb[(size_t)c * N_];
        l0 += xv * Wl[c] + fvv[cc] * Wl[256 + c];
        l1 += xv * Wl[512 + c] + fvv[cc] * Wl[768 + c];
    }
    l0r[cg][i] = l0;
    l1r[cg][i] = l1;
    __syncthreads();
    if (t < 16) {
        float L0 = 0.f, L1 = 0.f;
#pragma unroll
        for (int g = 0; g < 16; ++g) { L0 += l0r[g][t]; L1 += l1r[g][t]; }
        const float mx = fmaxf(L0, L1);
        const float e0 = expf(L0 - mx);
        const float e1 = expf(L1 - mx);
        const float inv = 1.0f / (e0 + e1);
        w0s[t] = e0 * inv;
        w1s[t] = e1 * inv;
    }
    __syncthreads();
    const float w0 = w0s[i], w1 = w1s[i];

#pragma unroll
    for (int cc = 0; cc < 16; ++cc) {
        const int c = cg * 16 + cc;
        const size_t off = (size_t)batch * CN_ + (size_t)c * N_ + n0 + i;
        const float xv = xb[(size_t)c * N_];  // L1-hot re-read
        out[off] = xv * w0 + fvv[cc] * w1;
        out[TOT_ + off] = fvv[cc];
    }
}

// ---------------------------------------------------------------------------
extern "C" void kernel_launch(void* const* d_in, const int* in_sizes, int n_in,
                              void* d_out, int out_size, void* d_ws, size_t ws_size,
                              hipStream_t stream) {
    const float* x = (const float*)d_in[0];
    const float* W = (const float*)d_in[1];
    float* out = (float*)d_out;

    const size_t BF_BYTES = (size_t)TOT_ * 2;             // 8.39 MB each
    const size_t NORM_BYTES = (size_t)B_ * N_ * 4;        // 64 KB
    const size_t P_BYTES = (size_t)B_ * NTILES * N_ * 4;  // 1 MB each

    uint8_t* p = (uint8_t*)d_ws;
    __hip_bfloat16* hiT = (__hip_bfloat16*)p; p += BF_BYTES;
    __hip_bfloat16* loT = (__hip_bfloat16*)p; p += BF_BYTES;
    float* rnorm = (float*)p; p += NORM_BYTES;
    float* normacc = (float*)p; p += NORM_BYTES;
    float* pval = (float*)p; p += P_BYTES;
    int* pidx = (int*)p; p += P_BYTES;
    float* pval2 = (float*)p; p += P_BYTES;
    int* fidx = (int*)p; p += NORM_BYTES;
    int* rcnt = (int*)p; p += 256;
    int* ridx = (int*)p; p += NORM_BYTES;
    unsigned long long* pbest = (unsigned long long*)p; p += (size_t)B_ * N_ * 8;

    hipMemsetAsync(rcnt, 0, 4, stream);
    hipMemsetAsync(normacc, 0, NORM_BYTES, stream);
    convert_kernel<<<1024, 256, 0, stream>>>(x, hiT, loT, normacc);
    rnorm_fin_kernel<<<64, 256, 0, stream>>>(normacc, rnorm);
    gram_mfma_kernel<<<B_ * NPAIRS, 256, 0, stream>>>(hiT, loT, rnorm, pval, pidx, pval2);
    combine_kernel<<<64, 256, 0, stream>>>(pval, pidx, pval2, fidx, rcnt, ridx, pbest);
    rescue_kernel<<<256, 256, 0, stream>>>(x, rnorm, rcnt, ridx, pbest);
    rescue_fin_kernel<<<64, 256, 0, stream>>>(pbest, rcnt, ridx, fidx);
    finish_kernel<<<1024, 256, 0, stream>>>(x, hiT, loT, W, fidx, out);
}

// Round 3
// 178.673 us; speedup vs baseline: 1.1737x; 1.0094x over previous
//
#include <hip/hip_runtime.h>
#include <hip/hip_bf16.h>
#include <math.h>

constexpr int B_ = 8;
constexpr int C_ = 256;
constexpr int N_ = 2048;
constexpr int CN_ = C_ * N_;        // 524288
constexpr int TOT_ = B_ * C_ * N_;  // 4194304
constexpr int NTILES = 16;          // 128-wide strips
constexpr int NPAIRS = 136;         // triangular tiles per batch

typedef __attribute__((ext_vector_type(8))) short bf16x8;
typedef __attribute__((ext_vector_type(4))) float f32x4;

__device__ __forceinline__ void g2l16(const void* g, void* l) {
    __builtin_amdgcn_global_load_lds(
        (const __attribute__((address_space(1))) void*)g,
        (__attribute__((address_space(3))) void*)l, 16, 0, 0);
}

__device__ __forceinline__ unsigned short bits(__hip_bfloat16 h) {
    union { __hip_bfloat16 b; unsigned short u; } cv;
    cv.b = h;
    return cv.u;
}

__device__ __forceinline__ float b2f(short s) {
    union { float f; unsigned u; } cv;
    cv.u = ((unsigned)(unsigned short)s) << 16;
    return cv.f;
}

// sortable packed key: (monotone float bits << 32) | (2047 - m)  [lower m wins ties]
__device__ __forceinline__ unsigned long long packkey(float v, int m) {
    const unsigned b = __float_as_uint(v);
    const unsigned u = (b & 0x80000000u) ? ~b : (b | 0x80000000u);
    return ((unsigned long long)u << 32) | (unsigned)(2047 - m);
}

// ----------------------------------------- convert (+ partial norms) -------
// grid = 1024 blocks (batch = blk&7 -> XCD-local), 256 threads.
// 64c x 64n tile: transpose, bf16 hi/lo split, atomic norm partial.
__global__ __launch_bounds__(256) void convert_kernel(const float* __restrict__ x,
                                                      __hip_bfloat16* __restrict__ hiT,
                                                      __hip_bfloat16* __restrict__ loT,
                                                      float* __restrict__ normacc) {
    const int blk = blockIdx.x;
    const int batch = blk & 7;
    const int nt = (blk >> 3) & 31;
    const int ctile = blk >> 8;
    const int n0 = nt << 6, c0 = ctile << 6;
    const int t = threadIdx.x;
    const int i = t & 63, j = t >> 6;

    __shared__ float tb[64][65];
    __shared__ float red[4][64];

    float s = 0.f;
    const float* xp = x + (size_t)batch * CN_ + (size_t)c0 * N_ + n0 + i;
#pragma unroll 4
    for (int r = 0; r < 16; ++r) {
        const int cl = j + r * 4;
        const float v = xp[(size_t)cl * N_];
        tb[cl][i] = v;
        s += v * v;
    }
    red[j][i] = s;
    __syncthreads();

    const int cp = t & 31;  // c-pair
    const int c2 = cp << 1;
    const int nb = t >> 5;  // 8 n-groups
#pragma unroll 4
    for (int r = 0; r < 8; ++r) {
        const int n = nb + r * 8;
        const float v0 = tb[c2][n], v1 = tb[c2 + 1][n];
        const size_t o = ((size_t)batch * N_ + n0 + n) * C_ + c0 + c2;
        const __hip_bfloat16 h0 = __float2bfloat16(v0);
        const __hip_bfloat16 h1 = __float2bfloat16(v1);
        const __hip_bfloat16 g0 = __float2bfloat16(v0 - __bfloat162float(h0));
        const __hip_bfloat16 g1 = __float2bfloat16(v1 - __bfloat162float(h1));
        ((unsigned*)hiT)[o >> 1] = ((unsigned)bits(h1) << 16) | bits(h0);
        ((unsigned*)loT)[o >> 1] = ((unsigned)bits(g1) << 16) | bits(g0);
    }
    if (j == 0) {
        const float tt = red[0][i] + red[1][i] + red[2][i] + red[3][i];
        atomicAdd(normacc + batch * N_ + n0 + i, tt);
    }
}

__global__ void rnorm_fin_kernel(const float* __restrict__ normacc,
                                 float* __restrict__ rnorm) {
    const int t = blockIdx.x * 256 + threadIdx.x;  // 16384
    rnorm[t] = 1.0f / sqrtf(normacc[t] + 256.0f * 1e-6f);
}

// ------------------------------- gram (MFMA, triangular) + argmax ----------
// grid = B * 136 blocks of 256 (4 waves); batch = blk & 7 (XCD-local L2).
// 128x128 tile, BK=32, bn<=bm. sim = hi*hi + hi*lo + lo*hi fused per K-pass:
// LDS rows pack [hi k0..31 | lo k0..31] (128B). Counted-vmcnt pipeline
// (T3+T4): raw s_barrier + hand s_waitcnt; prefetch loads stay in flight
// ACROSS barriers (vmcnt(8) steady-state, never 0 in main loop). 2-deep:
//   prologue: stage t0+t1; vmcnt(8); bar
//   iter kt:  ds_read buf[kt&1]; lgkmcnt(0); bar; stage kt+2 into same buf;
//             48 MFMA; vmcnt(8); bar
// Distinct __shared__ objects so alias analysis proves stage(next) vs
// ds_read(cur) independent. All per-lane addresses hoisted.
__global__ __launch_bounds__(256, 2) void gram_mfma_kernel(
        const __hip_bfloat16* __restrict__ hiT, const __hip_bfloat16* __restrict__ loT,
        const float* __restrict__ rnorm,
        float* __restrict__ pval, int* __restrict__ pidx, float* __restrict__ pval2) {
    const int blk = blockIdx.x;
    const int batch = blk & 7;
    int p = blk >> 3;  // 0..135
    int bn = 0;
    while (p >= NTILES - bn) { p -= NTILES - bn; ++bn; }
    const int bm = bn + p;
    const bool diag = (bn == bm);
    const int n0 = bn << 7, m0 = bm << 7;

    __shared__ short As0[128 * 64];
    __shared__ short As1[128 * 64];
    __shared__ short Bs0[128 * 64];
    __shared__ short Bs1[128 * 64];
    // epilogue arrays overlaid on As0 (safe: only used after kt=6 barriers;
    // kt=7 touches only As1/Bs1)
    short* ov = &As0[0];
    float (*rv1)[2] = (float(*)[2])(ov + 0);
    int (*ri1)[2] = (int(*)[2])(ov + 512);
    float (*rv2)[2] = (float(*)[2])(ov + 1024);
    float (*cv1)[2] = (float(*)[2])(ov + 1536);
    int (*ci1)[2] = (int(*)[2])(ov + 2048);
    float (*cv2)[2] = (float(*)[2])(ov + 2560);
    float* rnA = (float*)(ov + 3072);

    const int tid = threadIdx.x;
    const int l = tid & 63, w = tid >> 6;
    const int lm = l & 15, q = l >> 4;
    const int x7 = lm & 7;
    const int wn = (w >> 1) << 6, wm = (w & 1) << 6;

    // ---- hoisted per-lane stage addresses (loop-invariant) ----
    const size_t bbase = (size_t)batch * CN_;
    const short* gA[4];
    const short* gB[4];
    int ldsoff[4];
#pragma unroll
    for (int pp = 0; pp < 4; ++pp) {
        const int slot = tid + pp * 256;
        const int r = slot >> 3, sidx = slot & 7;
        const int sw = sidx ^ (r & 7);  // XOR swizzle (self-inverse)
        const short* base = (const short*)((sw < 4) ? hiT : loT);
        gA[pp] = base + bbase + (size_t)(n0 + r) * C_ + (sw & 3) * 8;
        gB[pp] = base + bbase + (size_t)(m0 + r) * C_ + (sw & 3) * 8;
        ldsoff[pp] = slot * 8;
    }
    // ---- hoisted per-lane ds_read offsets (shorts) ----
    int aoff[8], boff[8];  // [rt*2 + {hi,lo}]
#pragma unroll
    for (int rt = 0; rt < 4; ++rt) {
        const int ra = wn + rt * 16 + lm;
        const int rb = wm + rt * 16 + lm;
        aoff[rt * 2] = ra * 64 + ((q ^ x7) * 8);
        aoff[rt * 2 + 1] = ra * 64 + (((4 | q) ^ x7) * 8);
        boff[rt * 2] = rb * 64 + ((q ^ x7) * 8);
        boff[rt * 2 + 1] = rb * 64 + (((4 | q) ^ x7) * 8);
    }

    f32x4 acc[4][4];
#pragma unroll
    for (int rt = 0; rt < 4; ++rt)
#pragma unroll
        for (int ct = 0; ct < 4; ++ct) acc[rt][ct] = (f32x4){0.f, 0.f, 0.f, 0.f};

    // prologue: stage K-tiles 0 and 1 (16 loads); wait tile0 (8 newest in flight)
#pragma unroll
    for (int pp = 0; pp < 4; ++pp) {
        g2l16(gA[pp], As0 + ldsoff[pp]);
        g2l16(gB[pp], Bs0 + ldsoff[pp]);
    }
#pragma unroll
    for (int pp = 0; pp < 4; ++pp) {
        g2l16(gA[pp] + 32, As1 + ldsoff[pp]);
        g2l16(gB[pp] + 32, Bs1 + ldsoff[pp]);
    }
    asm volatile("s_waitcnt vmcnt(8)" ::: "memory");
    __builtin_amdgcn_sched_barrier(0);
    __builtin_amdgcn_s_barrier();
    __builtin_amdgcn_sched_barrier(0);

#pragma unroll
    for (int kt = 0; kt < 8; ++kt) {
        short* Ac = (kt & 1) ? As1 : As0;
        short* Bc = (kt & 1) ? Bs1 : Bs0;
        bf16x8 ah[4], al[4], bh[4], bl[4];
#pragma unroll
        for (int rt = 0; rt < 4; ++rt) {
            ah[rt] = *(const bf16x8*)(Ac + aoff[rt * 2]);
            al[rt] = *(const bf16x8*)(Ac + aoff[rt * 2 + 1]);
        }
#pragma unroll
        for (int ct = 0; ct < 4; ++ct) {
            bh[ct] = *(const bf16x8*)(Bc + boff[ct * 2]);
            bl[ct] = *(const bf16x8*)(Bc + boff[ct * 2 + 1]);
        }
        // my reads of buf[kt&1] complete -> all waves' reads complete at barrier
        asm volatile("s_waitcnt lgkmcnt(0)" ::: "memory");
        __builtin_amdgcn_sched_barrier(0);
        __builtin_amdgcn_s_barrier();
        __builtin_amdgcn_sched_barrier(0);
        if (kt < 6) {  // stage tile kt+2 into the buffer just freed
#pragma unroll
            for (int pp = 0; pp < 4; ++pp) {
                g2l16(gA[pp] + (kt + 2) * 32, Ac + ldsoff[pp]);
                g2l16(gB[pp] + (kt + 2) * 32, Bc + ldsoff[pp]);
            }
        }
#pragma unroll
        for (int rt = 0; rt < 4; ++rt)
#pragma unroll
            for (int ct = 0; ct < 4; ++ct) {
                acc[rt][ct] = __builtin_amdgcn_mfma_f32_16x16x32_bf16(
                    ah[rt], bh[ct], acc[rt][ct], 0, 0, 0);
                acc[rt][ct] = __builtin_amdgcn_mfma_f32_16x16x32_bf16(
                    ah[rt], bl[ct], acc[rt][ct], 0, 0, 0);
                acc[rt][ct] = __builtin_amdgcn_mfma_f32_16x16x32_bf16(
                    al[rt], bh[ct], acc[rt][ct], 0, 0, 0);
            }
        if (kt < 6) {
            // tile kt+1 complete; tile kt+2's 8 loads stay in flight across barrier
            asm volatile("s_waitcnt vmcnt(8)" ::: "memory");
        } else if (kt == 6) {
            asm volatile("s_waitcnt vmcnt(0)" ::: "memory");  // tile 7 complete
        }
        if (kt < 7) {
            __builtin_amdgcn_sched_barrier(0);
            __builtin_amdgcn_s_barrier();
            __builtin_amdgcn_sched_barrier(0);
        }
    }

    // As0 reads all drained at kt=6 (lgkmcnt+barrier); kt=7 used As1/Bs1 only.
    if (tid < 128) rnA[tid] = rnorm[batch * N_ + n0 + tid];

    // ---- row path: rows n (n-strip), candidates m (m-strip), scale rnorm[m]
    float rnm[4];
#pragma unroll
    for (int ct = 0; ct < 4; ++ct) rnm[ct] = rnorm[batch * N_ + m0 + wm + ct * 16 + lm];

#pragma unroll
    for (int rt = 0; rt < 4; ++rt) {
#pragma unroll
        for (int r = 0; r < 4; ++r) {
            const int nrow = n0 + wn + rt * 16 + q * 4 + r;
            float v1 = -3.4e38f, v2 = -3.4e38f;
            int i1 = 0x7fffffff;
#pragma unroll
            for (int ct = 0; ct < 4; ++ct) {
                const int m = m0 + wm + ct * 16 + lm;
                const float v = acc[rt][ct][r] * rnm[ct];
                if (m == nrow) continue;
                if (v > v1) { v2 = v1; v1 = v; i1 = m; }
                else if (v > v2) v2 = v;
            }
#pragma unroll
            for (int d = 1; d < 16; d <<= 1) {
                const float ov1 = __shfl_xor(v1, d, 64);
                const int oi1 = __shfl_xor(i1, d, 64);
                const float ov2 = __shfl_xor(v2, d, 64);
                if (ov1 > v1 || (ov1 == v1 && oi1 < i1)) {
                    v2 = fmaxf(v1, ov2); v1 = ov1; i1 = oi1;
                } else {
                    v2 = fmaxf(v2, ov1);
                }
            }
            if (lm == 0) {
                const int rloc = wn + rt * 16 + q * 4 + r;
                rv1[rloc][w & 1] = v1;
                ri1[rloc][w & 1] = i1;
                rv2[rloc][w & 1] = v2;
            }
        }
    }
    __syncthreads();  // rnA + rv* visible

    // ---- col path: rows m (m-strip), candidates n (n-strip), scale rnorm[n]
    if (!diag) {
        float rnn[4][4];
#pragma unroll
        for (int rt = 0; rt < 4; ++rt)
#pragma unroll
            for (int r = 0; r < 4; ++r) rnn[rt][r] = rnA[wn + rt * 16 + q * 4 + r];
#pragma unroll
        for (int ct = 0; ct < 4; ++ct) {
            float v1 = -3.4e38f, v2 = -3.4e38f;
            int i1 = 0x7fffffff;
#pragma unroll
            for (int rt = 0; rt < 4; ++rt) {
#pragma unroll
                for (int r = 0; r < 4; ++r) {
                    const float v = acc[rt][ct][r] * rnn[rt][r];
                    const int nn = n0 + wn + rt * 16 + q * 4 + r;
                    if (v > v1) { v2 = v1; v1 = v; i1 = nn; }
                    else if (v > v2) v2 = v;
                }
            }
#pragma unroll
            for (int d = 16; d < 64; d <<= 1) {
                const float ov1 = __shfl_xor(v1, d, 64);
                const int oi1 = __shfl_xor(i1, d, 64);
                const float ov2 = __shfl_xor(v2, d, 64);
                if (ov1 > v1 || (ov1 == v1 && oi1 < i1)) {
                    v2 = fmaxf(v1, ov2); v1 = ov1; i1 = oi1;
                } else {
                    v2 = fmaxf(v2, ov1);
                }
            }
            if (q == 0) {
                const int mloc = wm + ct * 16 + lm;
                cv1[mloc][w >> 1] = v1;
                ci1[mloc][w >> 1] = i1;
                cv2[mloc][w >> 1] = v2;
            }
        }
    }
    __syncthreads();

    if (tid < 128) {
        // row result -> slot bm, rows n-strip
        {
            float v1 = rv1[tid][0]; int i1 = ri1[tid][0]; float v2 = rv2[tid][0];
            const float ov1 = rv1[tid][1]; const int oi1 = ri1[tid][1]; const float ov2 = rv2[tid][1];
            if (ov1 > v1 || (ov1 == v1 && oi1 < i1)) { v2 = fmaxf(v1, ov2); v1 = ov1; i1 = oi1; }
            else v2 = fmaxf(v2, ov1);
            const size_t gi = (size_t)(batch * NTILES + bm) * N_ + n0 + tid;
            pval[gi] = v1; pidx[gi] = i1; pval2[gi] = v2;
        }
        // col result -> slot bn, rows m-strip
        if (!diag) {
            float v1 = cv1[tid][0]; int i1 = ci1[tid][0]; float v2 = cv2[tid][0];
            const float ov1 = cv1[tid][1]; const int oi1 = ci1[tid][1]; const float ov2 = cv2[tid][1];
            if (ov1 > v1 || (ov1 == v1 && oi1 < i1)) { v2 = fmaxf(v1, ov2); v1 = ov1; i1 = oi1; }
            else v2 = fmaxf(v2, ov1);
            const size_t gi = (size_t)(batch * NTILES + bn) * N_ + m0 + tid;
            pval[gi] = v1; pidx[gi] = i1; pval2[gi] = v2;
        }
    }
}

// -------------------------------------------------------------- combine ----
__global__ void combine_kernel(const float* __restrict__ pval, const int* __restrict__ pidx,
                               const float* __restrict__ pval2, int* __restrict__ fidx,
                               int* __restrict__ rcnt, int* __restrict__ ridx,
                               unsigned long long* __restrict__ pbest) {
    const int t = blockIdx.x * 256 + threadIdx.x;  // 16384
    const int batch = t >> 11, n = t & 2047;
    float v1 = -3.4e38f, v2 = -3.4e38f;
    int i1 = 0x7fffffff;
    for (int s = 0; s < NTILES; ++s) {
        const size_t gi = (size_t)(batch * NTILES + s) * N_ + n;
        const float ov1 = pval[gi]; const int oi1 = pidx[gi]; const float ov2 = pval2[gi];
        if (ov1 > v1 || (ov1 == v1 && oi1 < i1)) { v2 = fmaxf(v1, ov2); v1 = ov1; i1 = oi1; }
        else v2 = fmaxf(v2, ov1);
    }
    fidx[t] = i1;
    if (v1 - v2 < 1e-4f) {
        const int slot = atomicAdd(rcnt, 1);
        ridx[slot] = t;
        pbest[slot] = 0ull;
    }
}

// --------------------------------------------------------------- rescue ----
// Exact fp32 re-argmax for near-tie rows. Each work item = (row, 256-m chunk)
// so one row's 2MB L2 stream is split across 8 blocks; block-reduce then one
// packed-u64 atomicMax per (row, chunk-block).
__global__ __launch_bounds__(256) void rescue_kernel(const float* __restrict__ x,
                                                     const float* __restrict__ rnorm,
                                                     const int* __restrict__ rcnt,
                                                     const int* __restrict__ ridx,
                                                     unsigned long long* __restrict__ pbest) {
    const int cnt = *rcnt;
    const int nwork = cnt << 3;
    const int tid = threadIdx.x;
    __shared__ unsigned long long bk[256];
    for (int wi = blockIdx.x; wi < nwork; wi += gridDim.x) {
        const int rr = wi >> 3, ch = wi & 7;
        const int t = ridx[rr];
        const int batch = t >> 11, n = t & 2047;
        const int m = (ch << 8) + tid;
        const float* xb = x + (size_t)batch * CN_;
        float s0 = 0.f, s1 = 0.f, s2 = 0.f, s3 = 0.f;
        const float* xn = xb + n;
        const float* xm = xb + m;
#pragma unroll 4
        for (int c = 0; c < C_; c += 4) {
            s0 += xn[(size_t)(c + 0) * N_] * xm[(size_t)(c + 0) * N_];
            s1 += xn[(size_t)(c + 1) * N_] * xm[(size_t)(c + 1) * N_];
            s2 += xn[(size_t)(c + 2) * N_] * xm[(size_t)(c + 2) * N_];
            s3 += xn[(size_t)(c + 3) * N_] * xm[(size_t)(c + 3) * N_];
        }
        const float v = ((s0 + s1) + (s2 + s3)) * rnorm[batch * N_ + m];
        bk[tid] = (m == n) ? 0ull : packkey(v, m);
        __syncthreads();
        for (int sft = 128; sft > 0; sft >>= 1) {
            if (tid < sft) {
                const unsigned long long o = bk[tid + sft];
                if (o > bk[tid]) bk[tid] = o;
            }
            __syncthreads();
        }
        if (tid == 0) atomicMax(&pbest[rr], bk[0]);
        __syncthreads();
    }
}

__global__ void rescue_fin_kernel(const unsigned long long* __restrict__ pbest,
                                  const int* __restrict__ rcnt,
                                  const int* __restrict__ ridx,
                                  int* __restrict__ fidx) {
    const int rr = blockIdx.x * 256 + threadIdx.x;
    if (rr < *rcnt) {
        const unsigned long long k = pbest[rr];
        const int m = 2047 - (int)(unsigned)(k & 0xffffffffull);
        fidx[ridx[rr]] = m;
    }
}

// ------------------------------- finish: gate softmax + gather + outputs ---
// grid = 1024 blocks (batch = blk&7, 128 ntiles of 16 n), 256 threads.
__global__ __launch_bounds__(256) void finish_kernel(const float* __restrict__ x,
                                                     const __hip_bfloat16* __restrict__ hiT,
                                                     const __hip_bfloat16* __restrict__ loT,
                                                     const float* __restrict__ W,
                                                     const int* __restrict__ fidx,
                                                     float* __restrict__ out) {
    const int batch = blockIdx.x & 7;
    const int nt = blockIdx.x >> 3;  // 0..127
    const int n0 = nt << 4;
    const int t = threadIdx.x;
    const int i = t & 15, cg = t >> 4;  // cg 0..15, 16 c each

    __shared__ float Wl[1024];
    __shared__ int il[16];
    __shared__ float l0r[16][17], l1r[16][17];
    __shared__ float w0s[16], w1s[16];

    for (int u = t; u < 1024; u += 256) Wl[u] = W[u];
    if (t < 16) il[t] = fidx[batch * N_ + n0 + t];
    __syncthreads();

    const float* xb = x + (size_t)batch * CN_ + n0 + i;
    const int myidx = il[i];
    const size_t row = ((size_t)batch * N_ + myidx) * C_ + cg * 16;

    float fvv[16];
    {
        const bf16x8* hp = (const bf16x8*)(hiT + row);
        const bf16x8* lp = (const bf16x8*)(loT + row);
#pragma unroll
        for (int v8 = 0; v8 < 2; ++v8) {
            const bf16x8 h = hp[v8];
            const bf16x8 g = lp[v8];
#pragma unroll
            for (int e = 0; e < 8; ++e) fvv[v8 * 8 + e] = b2f(h[e]) + b2f(g[e]);
        }
    }

    float l0 = 0.f, l1 = 0.f;
#pragma unroll
    for (int cc = 0; cc < 16; ++cc) {
        const int c = cg * 16 + cc;
        const float xv = xb[(size_t)c * N_];
        l0 += xv * Wl[c] + fvv[cc] * Wl[256 + c];
        l1 += xv * Wl[512 + c] + fvv[cc] * Wl[768 + c];
    }
    l0r[cg][i] = l0;
    l1r[cg][i] = l1;
    __syncthreads();
    if (t < 16) {
        float L0 = 0.f, L1 = 0.f;
#pragma unroll
        for (int g = 0; g < 16; ++g) { L0 += l0r[g][t]; L1 += l1r[g][t]; }
        const float mx = fmaxf(L0, L1);
        const float e0 = expf(L0 - mx);
        const float e1 = expf(L1 - mx);
        const float inv = 1.0f / (e0 + e1);
        w0s[t] = e0 * inv;
        w1s[t] = e1 * inv;
    }
    __syncthreads();
    const float w0 = w0s[i], w1 = w1s[i];

#pragma unroll
    for (int cc = 0; cc < 16; ++cc) {
        const int c = cg * 16 + cc;
        const size_t off = (size_t)batch * CN_ + (size_t)c * N_ + n0 + i;
        const float xv = xb[(size_t)c * N_];  // L1-hot re-read
        out[off] = xv * w0 + fvv[cc] * w1;
        out[TOT_ + off] = fvv[cc];
    }
}

// ---------------------------------------------------------------------------
extern "C" void kernel_launch(void* const* d_in, const int* in_sizes, int n_in,
                              void* d_out, int out_size, void* d_ws, size_t ws_size,
                              hipStream_t stream) {
    const float* x = (const float*)d_in[0];
    const float* W = (const float*)d_in[1];
    float* out = (float*)d_out;

    const size_t BF_BYTES = (size_t)TOT_ * 2;             // 8.39 MB each
    const size_t NORM_BYTES = (size_t)B_ * N_ * 4;        // 64 KB
    const size_t P_BYTES = (size_t)B_ * NTILES * N_ * 4;  // 1 MB each

    uint8_t* p = (uint8_t*)d_ws;
    __hip_bfloat16* hiT = (__hip_bfloat16*)p; p += BF_BYTES;
    __hip_bfloat16* loT = (__hip_bfloat16*)p; p += BF_BYTES;
    float* rnorm = (float*)p; p += NORM_BYTES;
    float* normacc = (float*)p; p += NORM_BYTES;
    float* pval = (float*)p; p += P_BYTES;
    int* pidx = (int*)p; p += P_BYTES;
    float* pval2 = (float*)p; p += P_BYTES;
    int* fidx = (int*)p; p += NORM_BYTES;
    int* rcnt = (int*)p; p += 256;
    int* ridx = (int*)p; p += NORM_BYTES;
    unsigned long long* pbest = (unsigned long long*)p; p += (size_t)B_ * N_ * 8;

    hipMemsetAsync(rcnt, 0, 4, stream);
    hipMemsetAsync(normacc, 0, NORM_BYTES, stream);
    convert_kernel<<<1024, 256, 0, stream>>>(x, hiT, loT, normacc);
    rnorm_fin_kernel<<<64, 256, 0, stream>>>(normacc, rnorm);
    gram_mfma_kernel<<<B_ * NPAIRS, 256, 0, stream>>>(hiT, loT, rnorm, pval, pidx, pval2);
    combine_kernel<<<64, 256, 0, stream>>>(pval, pidx, pval2, fidx, rcnt, ridx, pbest);
    rescue_kernel<<<256, 256, 0, stream>>>(x, rnorm, rcnt, ridx, pbest);
    rescue_fin_kernel<<<64, 256, 0, stream>>>(pbest, rcnt, ridx, fidx);
    finish_kernel<<<1024, 256, 0, stream>>>(x, hiT, loT, W, fidx, out);
}